// Round 14
// baseline (1546.809 us; speedup 1.0000x reference)
//
#include <hip/hip_runtime.h>
#include <math.h>

#define UNITS 64
#define TT 100
#define NB 16            // batch rows per tile = one MFMA M-tile
#define NTH 256          // 4 waves; wave w owns unit-columns [16w,16w+16) for all 4 gates
#define HSTR 72          // hbuf row stride in halves
#define XQSTR 18         // xt quad stride per timestep (16 rows + 2 pad -> conflict-free)
#define NSORT 128        // sorter blocks (co-resident; internal barrier proven r11/r12)
#define CHROWS 128       // rows per sorter chunk
#define FLAG_MAGIC 0x7C0FFEE1   // != 0xAAAAAAAA poison, != 0
#define DONE_MAGIC 0x600DD0E5   // != poison

typedef _Float16 half8 __attribute__((ext_vector_type(8)));
typedef _Float16 half4 __attribute__((ext_vector_type(4)));
typedef float floatx4 __attribute__((ext_vector_type(4)));

#define LOG2E 1.44269504088896f

__device__ __forceinline__ float rcp_fast(float x) { return __builtin_amdgcn_rcpf(x); }
__device__ __forceinline__ float exp2_fast(float x) { return __builtin_amdgcn_exp2f(x); }

__device__ __forceinline__ float fast_sigmoid(float x) {
    return rcp_fast(1.0f + exp2_fast(-LOG2E * x));      // saturates correctly
}
__device__ __forceinline__ float fast_tanh(float x) {
    return __builtin_fmaf(2.0f, rcp_fast(1.0f + exp2_fast(-2.0f * LOG2E * x)), -1.0f);
}

__global__ __launch_bounds__(NTH, 4) void lstm_onenode_kernel(
    const float* __restrict__ x,    // (B,100,3)
    const float* __restrict__ W,    // (3,256)
    const float* __restrict__ U,    // (64,256)
    const float* __restrict__ bias, // (256,)
    const float* __restrict__ W1,   // (64,64)
    const float* __restrict__ b1,   // (64,)
    const float* __restrict__ W2,   // (64,5)
    const float* __restrict__ b2,   // (5,)
    int* __restrict__ histT,        // (101*NSORT)
    int* __restrict__ sflags,       // (NSORT) internal sort barrier
    int* __restrict__ doneCount,    // (1)
    int* __restrict__ doneFlag,     // (1)
    int* __restrict__ perm,         // (B,) rank -> row
    int* __restrict__ rlen,         // (B,) length at rank
    float* __restrict__ out, int B, int do_sort)
{
    // ---- LSTM shared state ----
    __shared__ __align__(16) _Float16 hb[2][NB * HSTR];
    __shared__ __align__(16) _Float16 xt[TT * XQSTR * 4];
    __shared__ __align__(16) _Float16 zq[8];
    __shared__ int shInt[2 * NB];
    __shared__ float h1buf[NB * 64];
    __shared__ float logitbuf[NB * 5];
    // ---- sorter shared state (sorters exit before LSTM phase; disjoint use) ----
    __shared__ int lh[TT + 1];
    __shared__ int llen_s[CHROWS];
    __shared__ int s_hist[TT + 1];
    __shared__ int s_rank0[TT + 1];
    __shared__ int s_cur[TT + 1];

    const int tid = threadIdx.x;
    const int bi  = blockIdx.x;

    if (do_sort && bi < NSORT) {
        // ================= SORTER BLOCK (round-12 proven body) =================
        const int grp = tid >> 4;
        const int sub = tid & 15;

        if (bi == 0 && tid == 0)
            __hip_atomic_store(doneCount, 0, __ATOMIC_RELAXED, __HIP_MEMORY_SCOPE_AGENT);

        for (int i = tid; i <= TT; i += 256) { lh[i] = 0; s_cur[i] = 0; }
        __syncthreads();

        // Phase A: lengths of rows [CHROWS*bi, CHROWS*bi+CHROWS)
        for (int pass = 0; pass < CHROWS / 16; ++pass) {
            const int row = bi * CHROWS + pass * 16 + grp;
            const float* xp = x + (size_t)row * (TT * 3);
            int m = 0;
            for (int t = sub; t < TT; t += 16) {
                const float a = xp[3*t], b = xp[3*t+1], c = xp[3*t+2];
                if (a != 0.0f || b != 0.0f || c != 0.0f) m = t + 1;
            }
            #pragma unroll
            for (int off = 8; off; off >>= 1) m = max(m, __shfl_down(m, off, 16));
            if (sub == 0) { llen_s[pass * 16 + grp] = m; atomicAdd(&lh[m], 1); }
        }
        __syncthreads();
        for (int i = tid; i <= TT; i += 256) histT[i * NSORT + bi] = lh[i];

        // internal barrier over the 128 co-resident sorter blocks (r11/r12 proven)
        __threadfence();
        __syncthreads();
        if (tid == 0)
            __hip_atomic_store(&sflags[bi], FLAG_MAGIC, __ATOMIC_RELEASE,
                               __HIP_MEMORY_SCOPE_AGENT);
        if (tid < NSORT) {
            while (__hip_atomic_load(&sflags[tid], __ATOMIC_ACQUIRE,
                                     __HIP_MEMORY_SCOPE_AGENT) != FLAG_MAGIC)
                __builtin_amdgcn_s_sleep(1);
        }
        __syncthreads();
        __threadfence();

        // Phase B: total hist, descending offsets, chunk bases
        for (int i = tid; i <= TT; i += 256) {
            int s = 0, base = 0;
            for (int pb = 0; pb < NSORT; ++pb) {
                const int v = histT[i * NSORT + pb];
                s += v;
                if (pb < bi) base += v;
            }
            s_hist[i] = s;
            s_rank0[i] = base;
        }
        __syncthreads();
        for (int i = tid; i <= TT; i += 256) {
            int s = 0;
            for (int k = i + 1; k <= TT; ++k) s += s_hist[k];
            s_rank0[i] += s;
        }
        __syncthreads();

        // scatter own CHROWS rows
        if (tid < CHROWS) {
            const int myl = llen_s[tid];
            const int ord = atomicAdd(&s_cur[myl], 1);
            const int r = s_rank0[myl] + ord;
            if (r >= 0 && r < B) { perm[r] = bi * CHROWS + tid; rlen[r] = myl; }
        }

        // publish completion: last sorter sets doneFlag (release)
        __threadfence();
        __syncthreads();
        if (tid == 0) {
            const int old = atomicAdd(doneCount, 1);
            if (old == NSORT - 1)
                __hip_atomic_store(doneFlag, DONE_MAGIC, __ATOMIC_RELEASE,
                                   __HIP_MEMORY_SCOPE_AGENT);
        }
        return;
    }

    // ================= LSTM BLOCK (round-11 proven body) =================
    const int w   = tid >> 6;
    const int l   = tid & 63;
    const int q   = l >> 4;
    const int cnl = l & 15;
    const int lb  = do_sort ? (bi - NSORT) : bi;
    const int b0  = lb * NB;
    const int grp = tid >> 4;
    const int sub = tid & 15;

    // ---- Bf preload FIRST: overlaps the sorters' work ----
    half8 Bf[4][3];
    #pragma unroll
    for (int g = 0; g < 4; ++g) {
        const int zc = 64 * g + 16 * w + cnl;
        #pragma unroll
        for (int kb = 0; kb < 3; ++kb)
            #pragma unroll
            for (int j = 0; j < 8; ++j) {
                const int k = 32 * kb + 8 * q + j;
                float v = 0.0f;
                if (k < 64)       v = U[k * 256 + zc];
                else if (k < 67)  v = W[(k - 64) * 256 + zc];
                else if (k == 67) v = bias[zc];
                Bf[g][kb][j] = (_Float16)v;
            }
    }
    if (tid < 8) zq[tid] = (_Float16)0.0f;
    for (int i = tid; i < NB * HSTR; i += NTH) hb[0][i] = (_Float16)0.0f;

    // ---- wait for sort completion (single-flag acquire; no grid barrier) ----
    if (do_sort) {
        while (__hip_atomic_load(doneFlag, __ATOMIC_ACQUIRE,
                                 __HIP_MEMORY_SCOPE_AGENT) != DONE_MAGIC)
            __builtin_amdgcn_s_sleep(4);
        __threadfence();
    }
    __syncthreads();

    if (tid < NB) {
        int g = do_sort ? perm[b0 + tid] : (b0 + tid);
        g = (g < 0) ? 0 : ((g >= B) ? (B - 1) : g);
        shInt[tid] = g;
        int ll = do_sort ? rlen[b0 + tid] : TT;
        shInt[NB + tid] = (ll < 0) ? 0 : ((ll > TT) ? TT : ll);
    }
    __syncthreads();   // shInt visible before ANY reader (round-7 lesson)

    int maxlen = shInt[NB];
    maxlen = (maxlen < 0) ? 0 : ((maxlen > TT) ? TT : maxlen);
    int minlen = shInt[NB + NB - 1];
    minlen = (minlen < 0) ? 0 : ((minlen > maxlen) ? maxlen : minlen);
    int rl[4];
    #pragma unroll
    for (int r = 0; r < 4; ++r) rl[r] = shInt[NB + 4*q + r];

    // ---- stage x tile as f16 quads {x0,x1,x2,1} ----
    {
        const float* xp = x + (size_t)shInt[grp] * (TT * 3);
        for (int t = sub; t < maxlen; t += 16) {
            const float a = xp[3*t], b = xp[3*t+1], c = xp[3*t+2];
            half4 v = { (_Float16)a, (_Float16)b, (_Float16)c, (_Float16)1.0f };
            *(half4*)&xt[(t * XQSTR + grp) * 4] = v;
        }
    }

    float c4[4] = {0.0f, 0.0f, 0.0f, 0.0f};
    _Float16 hcur[4] = {(_Float16)0.0f, (_Float16)0.0f, (_Float16)0.0f, (_Float16)0.0f};
    const floatx4 zero4 = {0.0f, 0.0f, 0.0f, 0.0f};

    __syncthreads();   // staging + hb[0] zero + zq visible

    int t = 0;

    // ---- unmasked main loop: all 16 rows live for t < minlen ----
    #pragma unroll 1
    for (; t < minlen; ++t) {
        const _Float16* hbc = hb[t & 1];
        _Float16*       hbn = hb[(t + 1) & 1];

        const half8 A0 = *(const half8*)&hbc[cnl * HSTR + 8 * q];
        const half8 A1 = *(const half8*)&hbc[cnl * HSTR + 32 + 8 * q];
        const _Float16* xaddr = (q == 0) ? &xt[(t * XQSTR + cnl) * 4] : zq;
        const half4 x4 = *(const half4*)xaddr;
        const half8 AX = { x4[0], x4[1], x4[2], x4[3],
                           (_Float16)0.0f, (_Float16)0.0f, (_Float16)0.0f, (_Float16)0.0f };

        floatx4 acc[4];
        #pragma unroll
        for (int g = 0; g < 4; ++g) {
            acc[g] = __builtin_amdgcn_mfma_f32_16x16x32_f16(AX, Bf[g][2], zero4, 0, 0, 0);
            acc[g] = __builtin_amdgcn_mfma_f32_16x16x32_f16(A0, Bf[g][0], acc[g], 0, 0, 0);
            acc[g] = __builtin_amdgcn_mfma_f32_16x16x32_f16(A1, Bf[g][1], acc[g], 0, 0, 0);
        }

        #pragma unroll
        for (int r = 0; r < 4; ++r) {
            const float iv = fast_sigmoid(acc[0][r]);
            const float fv = fast_sigmoid(acc[1][r]);
            const float gv = fast_tanh  (acc[2][r]);
            const float ov = fast_sigmoid(acc[3][r]);
            const float cn = fv * c4[r] + iv * gv;
            c4[r] = cn;
            hcur[r] = (_Float16)(ov * fast_tanh(cn));
            hbn[(4 * q + r) * HSTR + 16 * w + cnl] = hcur[r];
        }
        __syncthreads();
    }

    // ---- masked tail ----
    #pragma unroll 1
    for (; t < maxlen; ++t) {
        const _Float16* hbc = hb[t & 1];
        _Float16*       hbn = hb[(t + 1) & 1];

        const half8 A0 = *(const half8*)&hbc[cnl * HSTR + 8 * q];
        const half8 A1 = *(const half8*)&hbc[cnl * HSTR + 32 + 8 * q];
        const _Float16* xaddr = (q == 0) ? &xt[(t * XQSTR + cnl) * 4] : zq;
        const half4 x4 = *(const half4*)xaddr;
        const half8 AX = { x4[0], x4[1], x4[2], x4[3],
                           (_Float16)0.0f, (_Float16)0.0f, (_Float16)0.0f, (_Float16)0.0f };

        floatx4 acc[4];
        #pragma unroll
        for (int g = 0; g < 4; ++g) {
            acc[g] = __builtin_amdgcn_mfma_f32_16x16x32_f16(AX, Bf[g][2], zero4, 0, 0, 0);
            acc[g] = __builtin_amdgcn_mfma_f32_16x16x32_f16(A0, Bf[g][0], acc[g], 0, 0, 0);
            acc[g] = __builtin_amdgcn_mfma_f32_16x16x32_f16(A1, Bf[g][1], acc[g], 0, 0, 0);
        }

        #pragma unroll
        for (int r = 0; r < 4; ++r) {
            const bool live = (t < rl[r]);
            const float iv = fast_sigmoid(acc[0][r]);
            const float fv = fast_sigmoid(acc[1][r]);
            const float gv = fast_tanh  (acc[2][r]);
            const float ov = fast_sigmoid(acc[3][r]);
            const float cn = fv * c4[r] + iv * gv;
            c4[r] = live ? cn : c4[r];
            const _Float16 hn = (_Float16)(ov * fast_tanh(cn));
            hcur[r] = live ? hn : hcur[r];
            hbn[(4 * q + r) * HSTR + 16 * w + cnl] = hcur[r];
        }
        __syncthreads();
    }

    const _Float16* hbL = hb[maxlen & 1];

    // ---- epilogue: h1 = relu(h @ W1 + b1) ----
    {
        const int j  = tid & 63;
        const int bb = tid >> 6;
        const float bj = b1[j];
        #pragma unroll
        for (int p = 0; p < NB / 4; ++p) {
            const int b = p * 4 + bb;
            float acc = bj;
            #pragma unroll 8
            for (int k = 0; k < UNITS; ++k)
                acc += (float)hbL[b * HSTR + k] * W1[k * 64 + j];
            h1buf[b * 64 + j] = fmaxf(acc, 0.0f);
        }
    }
    __syncthreads();

    if (tid < NB * 5) {
        const int b = tid / 5, s = tid % 5;
        float acc = b2[s];
        for (int j = 0; j < 64; ++j)
            acc += h1buf[b * 64 + j] * W2[j * 5 + s];
        logitbuf[b * 5 + s] = acc;
    }
    __syncthreads();

    if (tid < NB) {
        const int gb = shInt[tid];
        const float l0 = logitbuf[tid * 5 + 0];
        const float l1 = logitbuf[tid * 5 + 1];
        const float l2 = logitbuf[tid * 5 + 2];
        const float l3 = logitbuf[tid * 5 + 3];
        const float l4 = logitbuf[tid * 5 + 4];
        const float m  = fmaxf(fmaxf(fmaxf(l0, l1), fmaxf(l2, l3)), l4);
        const float e0 = __expf(l0 - m), e1 = __expf(l1 - m), e2 = __expf(l2 - m);
        const float e3 = __expf(l3 - m), e4 = __expf(l4 - m);
        const float rs = 1.0f / (e0 + e1 + e2 + e3 + e4);
        out[(size_t)gb * 5 + 0] = e0 * rs;
        out[(size_t)gb * 5 + 1] = e1 * rs;
        out[(size_t)gb * 5 + 2] = e2 * rs;
        out[(size_t)gb * 5 + 3] = e3 * rs;
        out[(size_t)gb * 5 + 4] = e4 * rs;
    }
}

extern "C" void kernel_launch(void* const* d_in, const int* in_sizes, int n_in,
                              void* d_out, int out_size, void* d_ws, size_t ws_size,
                              hipStream_t stream) {
    const float* x  = (const float*)d_in[0];
    const float* W  = (const float*)d_in[1];
    const float* U  = (const float*)d_in[2];
    const float* b  = (const float*)d_in[3];
    const float* W1 = (const float*)d_in[4];
    const float* b1 = (const float*)d_in[5];
    const float* W2 = (const float*)d_in[6];
    const float* b2 = (const float*)d_in[7];
    float* out = (float*)d_out;

    const int B = in_sizes[0] / (TT * 3);   // 16384

    // workspace (ints): perm[B], rlen[B], histT[101*NSORT], sflags[NSORT],
    //                   doneCount[1], doneFlag[1]
    int* perm = nullptr; int* rlen = nullptr; int* histT = nullptr;
    int* sflags = nullptr; int* doneCount = nullptr; int* doneFlag = nullptr;
    const size_t need = ((size_t)2 * B + 101 * NSORT + NSORT + 2) * sizeof(int);
    const bool do_sort = (ws_size >= need) && (B == NSORT * CHROWS);
    if (do_sort) {
        perm      = (int*)d_ws;
        rlen      = perm + B;
        histT     = rlen + B;
        sflags    = histT + 101 * NSORT;
        doneCount = sflags + NSORT;
        doneFlag  = doneCount + 1;
    }

    const int nblk = B / NB + (do_sort ? NSORT : 0);   // 1024 LSTM (+128 sorters)
    lstm_onenode_kernel<<<dim3(nblk), dim3(NTH), 0, stream>>>(
        x, W, U, b, W1, b1, W2, b2,
        histT, sflags, doneCount, doneFlag, perm, rlen, out, B, do_sort ? 1 : 0);
}

// Round 15
// 213.871 us; speedup vs baseline: 7.2324x; 7.2324x over previous
//
#include <hip/hip_runtime.h>
#include <math.h>

#define UNITS 64
#define TT 100
#define NB 16          // batch rows per tile = one MFMA M-tile
#define NTH 256        // 4 waves; wave w owns unit-columns [16w,16w+16) for all 4 gates
#define HSTR 72        // hbuf row stride in halves
#define XQSTR 18       // xt quad stride per timestep (16 rows + 2 pad -> conflict-free)

typedef _Float16 half8 __attribute__((ext_vector_type(8)));
typedef _Float16 half4 __attribute__((ext_vector_type(4)));
typedef float floatx4 __attribute__((ext_vector_type(4)));

#define LOG2E 1.44269504088896f

__device__ __forceinline__ float rcp_fast(float x) { return __builtin_amdgcn_rcpf(x); }
__device__ __forceinline__ float exp2_fast(float x) { return __builtin_amdgcn_exp2f(x); }

__device__ __forceinline__ float fast_sigmoid(float x) {
    return rcp_fast(1.0f + exp2_fast(-LOG2E * x));      // saturates correctly
}
__device__ __forceinline__ float fast_tanh(float x) {
    return __builtin_fmaf(2.0f, rcp_fast(1.0f + exp2_fast(-2.0f * LOG2E * x)), -1.0f);
}

// Single-dispatch design note (rounds 5..14 ledger):
//  - every extra graph node costs ~30-75 us on this harness -> ONE node total.
//  - cross-block sync at 1024-block scale (coop grid.sync r8, spin barrier r13,
//    even a single producer->consumer flag r14) costs 300-1300 us -> NONE here.
//  - length-sorting never reduced LSTM wall-clock (r9/r11 112-115 us vs r6 120):
//    with an exactly-resident grid each CU runs ~max-tile steps (~100 slots)
//    regardless of sorted average (~61). E[max of 16 unif(20,100)] ~= 95. So the
//    sort bought nothing but overhead -> compute lengths per-block, run to tile max.
__global__ __launch_bounds__(NTH, 4) void lstm_kernel(
    const float* __restrict__ x,    // (B,100,3)
    const float* __restrict__ W,    // (3,256)
    const float* __restrict__ U,    // (64,256)
    const float* __restrict__ bias, // (256,)
    const float* __restrict__ W1,   // (64,64)
    const float* __restrict__ b1,   // (64,)
    const float* __restrict__ W2,   // (64,5)
    const float* __restrict__ b2,   // (5,)
    float* __restrict__ out, int B)
{
    __shared__ __align__(16) _Float16 hb[2][NB * HSTR];   // double-buffered h (f16)
    __shared__ __align__(16) _Float16 xt[TT * XQSTR * 4]; // staged x tile: quads {x0,x1,x2,1}
    __shared__ __align__(16) _Float16 zq[8];              // zero quad for q!=0 AX reads
    __shared__ int llen_s[NB];                            // per-row lengths (this tile)
    __shared__ float h1buf[NB * 64];
    __shared__ float logitbuf[NB * 5];

    const int tid = threadIdx.x;
    const int w   = tid >> 6;
    const int l   = tid & 63;
    const int q   = l >> 4;
    const int cnl = l & 15;
    const int b0  = blockIdx.x * NB;
    const int grp = tid >> 4;   // row within tile
    const int sub = tid & 15;   // lane within row

    // ---- in-block per-row lengths: 16 lanes/row, strided, coalesced ----
    {
        const float* xp = x + (size_t)(b0 + grp) * (TT * 3);
        int m = 0;
        for (int t = sub; t < TT; t += 16) {   // 12B/lane contiguous
            const float a = xp[3*t], b = xp[3*t+1], c = xp[3*t+2];
            if (a != 0.0f || b != 0.0f || c != 0.0f) m = t + 1;
        }
        #pragma unroll
        for (int off = 8; off; off >>= 1) m = max(m, __shfl_down(m, off, 16));
        if (sub == 0) llen_s[grp] = m;
    }
    if (tid < 8) zq[tid] = (_Float16)0.0f;
    for (int i = tid; i < NB * HSTR; i += NTH) hb[0][i] = (_Float16)0.0f;
    __syncthreads();   // llen_s visible before ANY reader (round-7 lesson)

    int maxlen = 0, minlen = TT;
    #pragma unroll
    for (int i = 0; i < NB; ++i) {             // LDS broadcast reads, cheap
        const int v = llen_s[i];
        maxlen = max(maxlen, v);
        minlen = min(minlen, v);
    }
    maxlen = (maxlen < 0) ? 0 : ((maxlen > TT) ? TT : maxlen);
    minlen = (minlen < 0) ? 0 : ((minlen > maxlen) ? maxlen : minlen);
    int rl[4];
    #pragma unroll
    for (int r = 0; r < 4; ++r) rl[r] = llen_s[4*q + r];

    // ---- stage x tile as f16 quads {x0,x1,x2,1} ----
    {
        const float* xp = x + (size_t)(b0 + grp) * (TT * 3);
        for (int t = sub; t < maxlen; t += 16) {
            const float a = xp[3*t], b = xp[3*t+1], c = xp[3*t+2];
            half4 v = { (_Float16)a, (_Float16)b, (_Float16)c, (_Float16)1.0f };
            *(half4*)&xt[(t * XQSTR + grp) * 4] = v;
        }
    }

    // ---- extended-K B fragments: rows 0..63=U, 64..66=W, 67=bias, 68..95=0.
    // B-frag (16x16x32): lane holds B[k=32kb+8q+j][zc].
    half8 Bf[4][3];
    #pragma unroll
    for (int g = 0; g < 4; ++g) {
        const int zc = 64 * g + 16 * w + cnl;
        #pragma unroll
        for (int kb = 0; kb < 3; ++kb)
            #pragma unroll
            for (int j = 0; j < 8; ++j) {
                const int k = 32 * kb + 8 * q + j;
                float v = 0.0f;
                if (k < 64)       v = U[k * 256 + zc];
                else if (k < 67)  v = W[(k - 64) * 256 + zc];
                else if (k == 67) v = bias[zc];
                Bf[g][kb][j] = (_Float16)v;
            }
    }

    float c4[4] = {0.0f, 0.0f, 0.0f, 0.0f};
    _Float16 hcur[4] = {(_Float16)0.0f, (_Float16)0.0f, (_Float16)0.0f, (_Float16)0.0f};
    const floatx4 zero4 = {0.0f, 0.0f, 0.0f, 0.0f};

    __syncthreads();   // staging + hb[0] zero + zq visible

    int t = 0;

    // ---- unmasked main loop: all 16 rows live for t < minlen ----
    #pragma unroll 1
    for (; t < minlen; ++t) {
        const _Float16* hbc = hb[t & 1];
        _Float16*       hbn = hb[(t + 1) & 1];

        const half8 A0 = *(const half8*)&hbc[cnl * HSTR + 8 * q];
        const half8 A1 = *(const half8*)&hbc[cnl * HSTR + 32 + 8 * q];
        const _Float16* xaddr = (q == 0) ? &xt[(t * XQSTR + cnl) * 4] : zq;
        const half4 x4 = *(const half4*)xaddr;
        const half8 AX = { x4[0], x4[1], x4[2], x4[3],
                           (_Float16)0.0f, (_Float16)0.0f, (_Float16)0.0f, (_Float16)0.0f };

        floatx4 acc[4];
        #pragma unroll
        for (int g = 0; g < 4; ++g) {
            acc[g] = __builtin_amdgcn_mfma_f32_16x16x32_f16(AX, Bf[g][2], zero4, 0, 0, 0);
            acc[g] = __builtin_amdgcn_mfma_f32_16x16x32_f16(A0, Bf[g][0], acc[g], 0, 0, 0);
            acc[g] = __builtin_amdgcn_mfma_f32_16x16x32_f16(A1, Bf[g][1], acc[g], 0, 0, 0);
        }

        #pragma unroll
        for (int r = 0; r < 4; ++r) {
            const float iv = fast_sigmoid(acc[0][r]);
            const float fv = fast_sigmoid(acc[1][r]);
            const float gv = fast_tanh  (acc[2][r]);
            const float ov = fast_sigmoid(acc[3][r]);
            const float cn = fv * c4[r] + iv * gv;
            c4[r] = cn;
            hcur[r] = (_Float16)(ov * fast_tanh(cn));
            hbn[(4 * q + r) * HSTR + 16 * w + cnl] = hcur[r];
        }
        __syncthreads();
    }

    // ---- masked tail: rows die as t reaches their length ----
    #pragma unroll 1
    for (; t < maxlen; ++t) {
        const _Float16* hbc = hb[t & 1];
        _Float16*       hbn = hb[(t + 1) & 1];

        const half8 A0 = *(const half8*)&hbc[cnl * HSTR + 8 * q];
        const half8 A1 = *(const half8*)&hbc[cnl * HSTR + 32 + 8 * q];
        const _Float16* xaddr = (q == 0) ? &xt[(t * XQSTR + cnl) * 4] : zq;
        const half4 x4 = *(const half4*)xaddr;
        const half8 AX = { x4[0], x4[1], x4[2], x4[3],
                           (_Float16)0.0f, (_Float16)0.0f, (_Float16)0.0f, (_Float16)0.0f };

        floatx4 acc[4];
        #pragma unroll
        for (int g = 0; g < 4; ++g) {
            acc[g] = __builtin_amdgcn_mfma_f32_16x16x32_f16(AX, Bf[g][2], zero4, 0, 0, 0);
            acc[g] = __builtin_amdgcn_mfma_f32_16x16x32_f16(A0, Bf[g][0], acc[g], 0, 0, 0);
            acc[g] = __builtin_amdgcn_mfma_f32_16x16x32_f16(A1, Bf[g][1], acc[g], 0, 0, 0);
        }

        #pragma unroll
        for (int r = 0; r < 4; ++r) {
            const bool live = (t < rl[r]);   // mask == (t < len): interior all-zero x measure 0
            const float iv = fast_sigmoid(acc[0][r]);
            const float fv = fast_sigmoid(acc[1][r]);
            const float gv = fast_tanh  (acc[2][r]);
            const float ov = fast_sigmoid(acc[3][r]);
            const float cn = fv * c4[r] + iv * gv;
            c4[r] = live ? cn : c4[r];
            const _Float16 hn = (_Float16)(ov * fast_tanh(cn));
            hcur[r] = live ? hn : hcur[r];
            hbn[(4 * q + r) * HSTR + 16 * w + cnl] = hcur[r];
        }
        __syncthreads();
    }

    const _Float16* hbL = hb[maxlen & 1];

    // ---- epilogue: h1 = relu(h @ W1 + b1) ----
    {
        const int j  = tid & 63;
        const int bb = tid >> 6;
        const float bj = b1[j];
        #pragma unroll
        for (int p = 0; p < NB / 4; ++p) {
            const int b = p * 4 + bb;
            float acc = bj;
            #pragma unroll 8
            for (int k = 0; k < UNITS; ++k)
                acc += (float)hbL[b * HSTR + k] * W1[k * 64 + j];
            h1buf[b * 64 + j] = fmaxf(acc, 0.0f);
        }
    }
    __syncthreads();

    if (tid < NB * 5) {
        const int b = tid / 5, s = tid % 5;
        float acc = b2[s];
        for (int j = 0; j < 64; ++j)
            acc += h1buf[b * 64 + j] * W2[j * 5 + s];
        logitbuf[b * 5 + s] = acc;
    }
    __syncthreads();

    if (tid < NB) {
        const int gb = b0 + tid;   // identity mapping — no permutation
        const float l0 = logitbuf[tid * 5 + 0];
        const float l1 = logitbuf[tid * 5 + 1];
        const float l2 = logitbuf[tid * 5 + 2];
        const float l3 = logitbuf[tid * 5 + 3];
        const float l4 = logitbuf[tid * 5 + 4];
        const float m  = fmaxf(fmaxf(fmaxf(l0, l1), fmaxf(l2, l3)), l4);
        const float e0 = __expf(l0 - m), e1 = __expf(l1 - m), e2 = __expf(l2 - m);
        const float e3 = __expf(l3 - m), e4 = __expf(l4 - m);
        const float rs = 1.0f / (e0 + e1 + e2 + e3 + e4);
        out[(size_t)gb * 5 + 0] = e0 * rs;
        out[(size_t)gb * 5 + 1] = e1 * rs;
        out[(size_t)gb * 5 + 2] = e2 * rs;
        out[(size_t)gb * 5 + 3] = e3 * rs;
        out[(size_t)gb * 5 + 4] = e4 * rs;
    }
}

extern "C" void kernel_launch(void* const* d_in, const int* in_sizes, int n_in,
                              void* d_out, int out_size, void* d_ws, size_t ws_size,
                              hipStream_t stream) {
    const float* x  = (const float*)d_in[0];
    const float* W  = (const float*)d_in[1];
    const float* U  = (const float*)d_in[2];
    const float* b  = (const float*)d_in[3];
    const float* W1 = (const float*)d_in[4];
    const float* b1 = (const float*)d_in[5];
    const float* W2 = (const float*)d_in[6];
    const float* b2 = (const float*)d_in[7];
    float* out = (float*)d_out;

    const int B = in_sizes[0] / (TT * 3);   // 16384

    lstm_kernel<<<dim3(B / NB), dim3(NTH), 0, stream>>>(
        x, W, U, b, W1, b1, W2, b2, out, B);
}